// Round 9
// baseline (53.164 us; speedup 1.0000x reference)
//
#include <hip/hip_runtime.h>
#include <hip/hip_bf16.h>

// TT-Rec embedding bag, MI355X. R8 version: quarter-tables resident in XCD L2.
// P=(100,100,100), Q=(4,4,8), R=(1,32,32,1), D=128, B=4096, H=50, n=204800.
//
//   AB table split by (m-half, s-half) into FOUR quarter-tables, 256 B rows
//   (8 m-rows x 16 s), 2.56 MB each -> fits a 4 MB XCD L2. Pool blocks are
//   XCD-steered (xcd = bid&7): XCD pair {2q,2q+1} owns quarter q, so each
//   XCD's gather working set is one L2-resident quarter. K=16 sub-contraction
//   runs on mfma_f32_16x16x32_bf16 with k>=16 zero-fed via NULL-row redirect
//   for lanes with kgroup>=2. 2 indices per MFMA (R7 scheme), +40-shfl
//   quadrant combine, atomicAdd epilogue onto memset-zeroed out.

#define P0 100
#define P1 100
#define P2 100
#define Q2 8
#define DIM 128
#define NPAIR (P0 * P1)
#define QT_STRIDE 2621440                   // bytes per quarter-table slot
#define NULL_A_BYTES (NPAIR * 256)          // zeroed row in each quarter table
#define NULL_B_BYTES (P2 * 256)             // zeroed row in each bfq table

typedef __attribute__((ext_vector_type(8))) short short8v;   // 8 bf16
typedef __attribute__((ext_vector_type(4))) float f32x4;

__device__ inline short f2bf(float x) {
    union { __hip_bfloat16 h; short s; } u;
    u.h = __float2bfloat16(x);
    return u.s;
}

// ---------------- K1: fused prep ----------------
__global__ __launch_bounds__(256) void prep(const int* __restrict__ lengths, int B,
                                            const float* __restrict__ core0,
                                            const float* __restrict__ core1,
                                            const float* __restrict__ core2,
                                            int* __restrict__ offsets,
                                            char* __restrict__ bfq0,
                                            char* __restrict__ bfq1,
                                            char* __restrict__ qt) {
    int bid = blockIdx.x;
    int t = threadIdx.x;
    if (bid == 0) {
        // ---- zero NULL rows (256 B = 128 shorts each) ----
        if (t < 128) {
#pragma unroll
            for (int qi = 0; qi < 4; ++qi)
                ((short*)(qt + (size_t)qi * QT_STRIDE))[NPAIR * 128 + t] = 0;
            ((short*)bfq0)[P2 * 128 + t] = 0;
            ((short*)bfq1)[P2 * 128 + t] = 0;
        }
        // ---- exclusive scan of lengths ----
        __shared__ int part[256];
        int per = (B + 255) / 256;
        int s = 0;
        for (int k = 0; k < per; ++k) {
            int i = t * per + k;
            s += (i < B) ? lengths[i] : 0;
        }
        part[t] = s;
        __syncthreads();
        for (int d = 1; d < 256; d <<= 1) {
            int v = (t >= d) ? part[t - d] : 0;
            __syncthreads();
            part[t] += v;
            __syncthreads();
        }
        int run = part[t] - s;
        for (int k = 0; k < per; ++k) {
            int i = t * per + k;
            if (i < B) { offsets[i] = run; run += lengths[i]; }
        }
        if (t == 255) offsets[B] = part[255];
    } else if (bid <= P2) {
        // ---- bfq prepack: for s-half s2, elem e = kg*64 + c3*8 + j holds
        // C[s2*16 + kg*8 + j][c3]  (kg in {0,1}, j in 0..7, c3 in 0..7)
        int i3 = bid - 1;
        int s2 = t >> 7;
        int e = t & 127;
        int kg = e >> 6, c3 = (e >> 3) & 7, j = e & 7;
        float v = core2[(size_t)i3 * 256 + (s2 * 16 + kg * 8 + j) * Q2 + c3];
        short* dst = (short*)(s2 ? bfq1 : bfq0);
        dst[(size_t)i3 * 128 + e] = f2bf(v);
    } else {
        // ---- AB build via MFMA: g in [0,200): i2 = g>>1, wave ct = (g&1)*4+w ----
        int g = bid - 1 - P2;
        int i2 = g >> 1;
        int w = t >> 6, lane = t & 63;
        int ct = (g & 1) * 4 + w;            // 0..7 (column tile of 16)
        int h = lane >> 4;                   // k-group (0..3) -> k = h*8+j
        int c16 = lane & 15;

        // B-frag once per wave: B[k][col] = core1[i2][k*128 + col], col = ct*16+c16
        const float* bbase = core1 + (size_t)i2 * 4096 + (h * 8) * 128 + ct * 16 + c16;
        short8v bfr;
#pragma unroll
        for (int j = 0; j < 8; ++j) bfr[j] = f2bf(bbase[j * 128]);

        int col = ct * 16 + c16;
        int cs = col >> 5;                   // b_ (0..3)
        int s = col & 31;                    // r2 index
        int s2 = s >> 4, sl = s & 15;
        for (int rt = 0; rt < 25; ++rt) {
            // A-frag: row R = rt*16 + c16 -> i1 = rt*4 + (c16>>2), a_ = c16&3
            const float* abase = core0 + (size_t)(rt * 4 + (c16 >> 2)) * 128
                                 + (c16 & 3) * 32 + h * 8;
            f32x4 x0 = *(const f32x4*)abase;
            f32x4 x1 = *(const f32x4*)(abase + 4);
            short8v afr;
#pragma unroll
            for (int j = 0; j < 4; ++j) { afr[j] = f2bf(x0[j]); afr[j + 4] = f2bf(x1[j]); }

            f32x4 d = __builtin_amdgcn_mfma_f32_16x16x32_bf16(
                afr, bfr, (f32x4){0.f, 0.f, 0.f, 0.f}, 0, 0, 0);

            // D row = h*4 + q; i1 = rt*4 + h, a_ = q -> m = q*4 + cs.
            int pair = (rt * 4 + h) * P1 + i2;
#pragma unroll
            for (int q = 0; q < 4; ++q) {
                int m = q * 4 + cs;
                short* tbl = (short*)(qt + (size_t)((m >> 3) * 2 + s2) * QT_STRIDE);
                tbl[(size_t)pair * 128 + (m & 7) * 16 + sl] = f2bf(d[q]);
            }
        }
    }
}

// ---------------- K2: bag pooling, quarter tables, 2 idx per MFMA ----------------
// 256 threads = 4 waves. xcd = bid&7 -> quarter = xcd>>1 (mh = q>>1, s2 = q&1),
// sub = xcd&1. Block covers bags g*8 + sub*4 + w for g = bid>>3.
__global__ __launch_bounds__(256) void bag_pool(const int* __restrict__ indices, int n,
                                                const int* __restrict__ offsets, int B,
                                                const char* __restrict__ qt,
                                                const char* __restrict__ bfq0,
                                                const char* __restrict__ bfq1,
                                                float* __restrict__ out) {
    int w = threadIdx.x >> 6;
    int lane = threadIdx.x & 63;
    int xcd = blockIdx.x & 7;
    int g = blockIdx.x >> 3;
    int quarter = xcd >> 1;
    int mh = quarter >> 1, s2 = quarter & 1;
    int bag = g * 8 + (xcd & 1) * 4 + w;
    if (bag >= B) return;

    const char* tbl = qt + (size_t)quarter * QT_STRIDE;
    const char* bfq = s2 ? bfq1 : bfq0;

    int start = offsets[bag];
    int end = offsets[bag + 1];
    if (bag == B - 1 && end < n) end = n;   // jnp.repeat pads with last bag id
    if (end > n) end = n;
    if (start > n) start = n;
    if (end < start) end = start;
    int cnt = end - start;

    int sel = (lane >> 3) & 1;               // A-row/B-col: idx j vs j+1
    bool lowk = (lane >> 4) < 2;             // kgroup<2 carries real k (0..15)
    int aoff = (lane & 7) * 32 + ((lane >> 4) & 1) * 16;
    int boff = (lane & 7) * 16 + ((lane >> 4) & 1) * 128;

    f32x4 acc0 = {0.f, 0.f, 0.f, 0.f};
    f32x4 acc1 = {0.f, 0.f, 0.f, 0.f};

    for (int cb = 0; cb < cnt; cb += 64) {
        int m = cnt - cb;
        if (m > 64) m = 64;
        unsigned idx = 0;
        if (lane < m) idx = (unsigned)indices[start + cb + lane];
        unsigned p = idx / 100u;                 // magic-mul
        unsigned i3 = idx - p * 100u;
        int abo = (int)(p << 8);                 // 256 B quarter rows
        int bfo = (lane < m) ? (int)(i3 << 8) : NULL_B_BYTES;

        int j = 0;
        for (; j + 3 < m; j += 4) {
            int A0 = __shfl(abo, j),     B0 = __shfl(bfo, j);
            int A1 = __shfl(abo, j + 1), B1 = __shfl(bfo, j + 1);
            int A2 = __shfl(abo, j + 2), B2 = __shfl(bfo, j + 2);
            int A3 = __shfl(abo, j + 3), B3 = __shfl(bfo, j + 3);
            int Ae = lowk ? (sel ? A1 : A0) : NULL_A_BYTES;
            int Be = lowk ? (sel ? B1 : B0) : NULL_B_BYTES;
            int Af = lowk ? (sel ? A3 : A2) : NULL_A_BYTES;
            int Bf = lowk ? (sel ? B3 : B2) : NULL_B_BYTES;
            short8v a0 = *(const short8v*)(tbl + Ae + aoff);
            short8v b0 = *(const short8v*)(bfq + Be + boff);
            short8v a1 = *(const short8v*)(tbl + Af + aoff);
            short8v b1 = *(const short8v*)(bfq + Bf + boff);
            acc0 = __builtin_amdgcn_mfma_f32_16x16x32_bf16(a0, b0, acc0, 0, 0, 0);
            acc1 = __builtin_amdgcn_mfma_f32_16x16x32_bf16(a1, b1, acc1, 0, 0, 0);
        }
        for (; j < m; j += 2) {
            // pair (j, j+1); if j+1 == m the pad lane holds NULL -> adds zero
            int A0 = __shfl(abo, j),     B0 = __shfl(bfo, j);
            int A1 = __shfl(abo, j + 1), B1 = __shfl(bfo, j + 1);
            int Ae = lowk ? (sel ? A1 : A0) : NULL_A_BYTES;
            int Be = lowk ? (sel ? B1 : B0) : NULL_B_BYTES;
            short8v a0 = *(const short8v*)(tbl + Ae + aoff);
            short8v b0 = *(const short8v*)(bfq + Be + boff);
            acc0 = __builtin_amdgcn_mfma_f32_16x16x32_bf16(a0, b0, acc0, 0, 0, 0);
        }
    }
    f32x4 acc = acc0 + acc1;

    // Q1 = rows 0-7 x cols 0-7 (idx even); Q2 = rows 8-15 x cols 8-15 (idx odd);
    // Q2 lane = Q1 lane + 40.
#pragma unroll
    for (int q = 0; q < 4; ++q) {
        float o = __shfl(acc[q], (lane + 40) & 63);
        acc[q] += o;
    }
    int hi = lane >> 4, c3 = lane & 15;
    if (hi < 2 && c3 < 8) {
        float* obase = out + (size_t)bag * DIM;
#pragma unroll
        for (int q = 0; q < 4; ++q) {
            int d = (mh * 8 + hi * 4 + q) * 8 + c3;
            atomicAdd(obase + d, acc[q]);
        }
    }
}

// ---------------- fallback (ws too small): direct VALU, equal-length bags ----------------
__global__ __launch_bounds__(128) void fallback_pool(const int* __restrict__ indices,
                                                     int n, int B,
                                                     const float* __restrict__ core0,
                                                     const float* __restrict__ core1,
                                                     const float* __restrict__ core2,
                                                     float* __restrict__ out) {
    int bag = blockIdx.x;
    int d = threadIdx.x;
    int m = d >> 3, c3 = d & 7;
    int a_ = m >> 2, b_ = m & 3;
    int H = n / B;
    float acc = 0.f;
    for (int j = bag * H; j < (bag + 1) * H; ++j) {
        int idx = indices[j];
        int i1 = idx / (P1 * P2);
        int rem = idx - i1 * (P1 * P2);
        int i2 = rem / P2;
        int i3 = rem - i2 * P2;
        const float* a = core0 + (size_t)i1 * 128;
        const float* b = core1 + (size_t)i2 * 4096;
        const float* c = core2 + (size_t)i3 * 256;
        float e = 0.f;
        for (int s = 0; s < 32; ++s) {
            float abv = 0.f;
            for (int r = 0; r < 32; ++r)
                abv += a[a_ * 32 + r] * b[r * 128 + b_ * 32 + s];
            e += abv * c[s * 8 + c3];
        }
        acc += e;
    }
    out[(size_t)bag * DIM + d] = acc;
}

extern "C" void kernel_launch(void* const* d_in, const int* in_sizes, int n_in,
                              void* d_out, int out_size, void* d_ws, size_t ws_size,
                              hipStream_t stream) {
    const int* indices = (const int*)d_in[0];
    const int* lengths = (const int*)d_in[1];
    const float* core0 = (const float*)d_in[2];
    const float* core1 = (const float*)d_in[3];
    const float* core2 = (const float*)d_in[4];
    float* out = (float*)d_out;
    int n = in_sizes[0];
    int B = in_sizes[1];

    const size_t OFF_OFFSETS = 0;                    // (B+1) ints
    const size_t OFF_BFQ0 = 32768;                   // (100+1)*256 B
    const size_t OFF_BFQ1 = 65536;                   // (100+1)*256 B
    const size_t OFF_Q = 131072;                     // 4 quarter tables
    const size_t REQ = OFF_Q + 4ull * QT_STRIDE;

    if (ws_size >= REQ) {
        int* offsets = (int*)((char*)d_ws + OFF_OFFSETS);
        char* bfq0 = (char*)d_ws + OFF_BFQ0;
        char* bfq1 = (char*)d_ws + OFF_BFQ1;
        char* qt = (char*)d_ws + OFF_Q;

        hipMemsetAsync(d_out, 0, (size_t)out_size * sizeof(float), stream);
        prep<<<1 + P2 + 200, 256, 0, stream>>>(lengths, B, core0, core1, core2,
                                               offsets, bfq0, bfq1, qt);
        int grid = ((B + 7) / 8) * 8;
        bag_pool<<<grid, 256, 0, stream>>>(indices, n, offsets, B,
                                           (const char*)qt, (const char*)bfq0,
                                           (const char*)bfq1, out);
    } else {
        fallback_pool<<<B, 128, 0, stream>>>(indices, n, B, core0, core1, core2, out);
    }
}